// Round 8
// baseline (799.260 us; speedup 1.0000x reference)
//
#include <hip/hip_runtime.h>

typedef unsigned int uint32;
typedef __attribute__((ext_vector_type(8))) short short8v;  // 8 bf16 (4 VGPRs)
typedef __attribute__((ext_vector_type(4))) float f32x4;

__device__ __forceinline__ unsigned short f2bf(float f) {
  unsigned u = __float_as_uint(f);
  return (unsigned short)((u + 0x7FFFu + ((u >> 16) & 1u)) >> 16);
}
__device__ __forceinline__ float bfl(unsigned x) { return __uint_as_float(x << 16); }
__device__ __forceinline__ float bfh(unsigned x) { return __uint_as_float(x & 0xFFFF0000u); }

// Generation-based grid barrier on device-scope (agent) atomics. Requires all
// blocks co-resident: guaranteed by __launch_bounds__(256,4) + grid <= 4*numCU.
// Bounded spin as a safety valve: wrong answer beats a hung harness.
__device__ __forceinline__ void grid_barrier(int* cnt, int* gen) {
  __syncthreads();
  if (threadIdx.x == 0) {
    __threadfence();  // release: prior global writes visible device-wide
    int g = __hip_atomic_load(gen, __ATOMIC_RELAXED, __HIP_MEMORY_SCOPE_AGENT);
    int arrived = __hip_atomic_fetch_add(cnt, 1, __ATOMIC_ACQ_REL, __HIP_MEMORY_SCOPE_AGENT);
    if (arrived == (int)gridDim.x - 1) {
      __hip_atomic_store(cnt, 0, __ATOMIC_RELAXED, __HIP_MEMORY_SCOPE_AGENT);
      __hip_atomic_fetch_add(gen, 1, __ATOMIC_ACQ_REL, __HIP_MEMORY_SCOPE_AGENT);
    } else {
      int spins = 0;
      while (__hip_atomic_load(gen, __ATOMIC_ACQUIRE, __HIP_MEMORY_SCOPE_AGENT) == g) {
        __builtin_amdgcn_s_sleep(2);
        if (++spins > (1 << 23)) break;
      }
    }
    __threadfence();
  }
  __syncthreads();
}

// P2 helper: one LANE per edge. Coalesced 32B idx + mask loads, 8 scalar sigma
// gathers (L2-resident 400KB table), in-lane softmax, atomicAdd att into W8[n][a]
// (3.6M atomics spread over 3.2MB -> low contention; proven fine in R4).
template <int MSZ>
__device__ __forceinline__ void edge_attend(const int* __restrict__ elist,
                                            const void* __restrict__ maskp,
                                            const float* __restrict__ sigma,
                                            float* __restrict__ W8, int m) {
  const int4 ia = ((const int4*)elist)[m * 2];
  const int4 ib = ((const int4*)elist)[m * 2 + 1];
  const int idx[8] = {ia.x, ia.y, ia.z, ia.w, ib.x, ib.y, ib.z, ib.w};
  int vld[8];
  if (MSZ == 4) {
    const int4 ma = ((const int4*)maskp)[m * 2];
    const int4 mb = ((const int4*)maskp)[m * 2 + 1];
    vld[0] = ma.x; vld[1] = ma.y; vld[2] = ma.z; vld[3] = ma.w;
    vld[4] = mb.x; vld[5] = mb.y; vld[6] = mb.z; vld[7] = mb.w;
  } else {
    const uint2 u = ((const uint2*)maskp)[m];
    vld[0] = u.x & 0xFF; vld[1] = (u.x >> 8) & 0xFF;
    vld[2] = (u.x >> 16) & 0xFF; vld[3] = u.x >> 24;
    vld[4] = u.y & 0xFF; vld[5] = (u.y >> 8) & 0xFF;
    vld[6] = (u.y >> 16) & 0xFF; vld[7] = u.y >> 24;
  }
  float sg[8];
  #pragma unroll
  for (int a = 0; a < 8; ++a) sg[a] = sigma[idx[a]];
  float mx = -3.0e38f;
  #pragma unroll
  for (int a = 0; a < 8; ++a) mx = fmaxf(mx, vld[a] ? sg[a] : -3.0e38f);
  float ev[8];
  float dn = 0.f;
  #pragma unroll
  for (int a = 0; a < 8; ++a) {
    ev[a] = vld[a] ? __expf(sg[a] - mx) : 0.f;
    dn += ev[a];
  }
  const float inv = __fdividef(1.f, dn);
  #pragma unroll
  for (int a = 0; a < 8; ++a)
    if (vld[a]) atomicAdd(&W8[(size_t)idx[a] * 8 + a], ev[a] * inv);
}

__global__ __launch_bounds__(256, 4) void fused_all(
    const float* __restrict__ X, const float* __restrict__ W,
    const float* __restrict__ a1, const int* __restrict__ elist,
    const void* __restrict__ maskp, unsigned short* __restrict__ Wh,
    float* __restrict__ sigma, float* __restrict__ W8,
    int* __restrict__ bar, int* __restrict__ flag,
    float* __restrict__ partial, float* __restrict__ out, int N, int M) {
  __shared__ short sB[2048 * 8];  // 32 KiB: P1 W-fragments; P3 reuses as reduce buf
  const int tid = threadIdx.x;
  const int gtid = blockIdx.x * 256 + tid;
  const int nthreads = gridDim.x * 256;
  const int lane = tid & 63;
  const int wv = tid >> 6;

  // ---- P0: detect mask element size (1B bool vs 4B). W8/bar zeroed by memset. ----
  if (blockIdx.x == 0 && tid < 64) {
    const uint32* md = (const uint32*)maskp;
    bool ok4 = true;
    for (int i = tid; i < 1024; i += 64) {
      uint32 v = md[i];
      if (!(v == 0u || v == 1u || v == 0x3F800000u)) ok4 = false;
    }
    bool all4 = __all(ok4);
    if (tid == 0)
      __hip_atomic_store(flag, all4 ? 4 : 1, __ATOMIC_RELAXED, __HIP_MEMORY_SCOPE_AGENT);
  }

  // ---- P1: Wh = X @ W1 via mfma_f32_16x16x32_bf16, + sigma epilogue ----
  for (int i = tid; i < 2048; i += 256) {
    const int frag = i >> 6, ln = i & 63;
    const int kt = frag >> 3, ct = frag & 7, p = ln >> 4, q = ln & 15;
    short8v v;
    #pragma unroll
    for (int j = 0; j < 8; ++j)
      v[j] = (short)f2bf(W[(kt * 32 + p * 8 + j) * 128 + ct * 16 + q]);
    *(short8v*)&sB[i * 8] = v;
  }
  __syncthreads();
  {
    const int p = lane >> 4, q = lane & 15;
    float a1v[8];
    #pragma unroll
    for (int ct = 0; ct < 8; ++ct) a1v[ct] = a1[ct * 16 + q];
    const int wave = blockIdx.x * 4 + wv;
    const int nwaves = gridDim.x * 4;
    const int nstrips = (N + 15) >> 4;
    for (int s = wave; s < nstrips; s += nwaves) {
      const int row = s * 16 + q;
      const int rclamp = row < N ? row : (N - 1);
      const float* xr = X + (size_t)rclamp * 128 + p * 8;
      float4 L[8];
      #pragma unroll
      for (int kt = 0; kt < 4; ++kt) {
        L[2 * kt]     = *(const float4*)(xr + kt * 32);
        L[2 * kt + 1] = *(const float4*)(xr + kt * 32 + 4);
      }
      short8v A[4];
      #pragma unroll
      for (int kt = 0; kt < 4; ++kt) {
        #pragma unroll
        for (int j = 0; j < 4; ++j) {
          A[kt][j]     = (short)f2bf((&L[2 * kt].x)[j]);
          A[kt][j + 4] = (short)f2bf((&L[2 * kt + 1].x)[j]);
        }
      }
      f32x4 acc[8];
      #pragma unroll
      for (int ct = 0; ct < 8; ++ct) acc[ct] = (f32x4){0.f, 0.f, 0.f, 0.f};
      #pragma unroll
      for (int kt = 0; kt < 4; ++kt) {
        #pragma unroll
        for (int ct = 0; ct < 8; ++ct) {
          short8v b = *(const short8v*)&sB[((kt * 8 + ct) * 64 + lane) * 8];
          acc[ct] = __builtin_amdgcn_mfma_f32_16x16x32_bf16(A[kt], b, acc[ct], 0, 0, 0);
        }
      }
      const int r0 = s * 16 + p * 4;
      #pragma unroll
      for (int ct = 0; ct < 8; ++ct) {
        #pragma unroll
        for (int r = 0; r < 4; ++r) {
          const int rr = r0 + r;
          if (rr < N) Wh[(size_t)rr * 128 + ct * 16 + q] = f2bf(acc[ct][r]);
        }
      }
      #pragma unroll
      for (int r = 0; r < 4; ++r) {
        float tsum = 0.f;
        #pragma unroll
        for (int ct = 0; ct < 8; ++ct) {
          const float v = acc[ct][r];
          tsum += fmaxf(v, 0.2f * v) * a1v[ct];
        }
        tsum += __shfl_xor(tsum, 1);
        tsum += __shfl_xor(tsum, 2);
        tsum += __shfl_xor(tsum, 4);
        tsum += __shfl_xor(tsum, 8);
        const int rr = r0 + r;
        if (q == r && rr < N) sigma[rr] = tsum;
      }
    }
  }

  grid_barrier(bar, bar + 16);

  // ---- P2: per-edge softmax -> W8 atomics (one lane per edge) ----
  {
    const int msz = __hip_atomic_load(flag, __ATOMIC_RELAXED, __HIP_MEMORY_SCOPE_AGENT);
    if (msz == 4) {
      for (int m = gtid; m < M; m += nthreads)
        edge_attend<4>(elist, maskp, sigma, W8, m);
    } else {
      for (int m = gtid; m < M; m += nthreads)
        edge_attend<1>(elist, maskp, sigma, W8, m);
    }
  }

  grid_barrier(bar, bar + 16);

  // ---- P3: partial[b][a][f] = sum_n W8[n][a] * Wh[n][f] (streaming, PLAIN stores) ----
  {
    const uint32* Wh32 = (const uint32*)Wh;
    float* sAcc = (float*)sB;  // [4][1024] = 16 KiB
    const int wave = blockIdx.x * 4 + wv;
    const int nw = gridDim.x * 4;
    float acc[16];
    #pragma unroll
    for (int j = 0; j < 16; ++j) acc[j] = 0.f;

    for (int n = wave; n < N; n += 2 * nw) {
      const int n2 = n + nw;
      const uint32 d0 = Wh32[(size_t)n * 64 + lane];
      const float4 wa0 = *(const float4*)&W8[(size_t)n * 8];
      const float4 wb0 = *(const float4*)&W8[(size_t)n * 8 + 4];
      uint32 d1 = 0;
      float4 wa1 = {0.f, 0.f, 0.f, 0.f}, wb1 = {0.f, 0.f, 0.f, 0.f};
      if (n2 < N) {
        d1 = Wh32[(size_t)n2 * 64 + lane];
        wa1 = *(const float4*)&W8[(size_t)n2 * 8];
        wb1 = *(const float4*)&W8[(size_t)n2 * 8 + 4];
      }
      const float lo0 = bfl(d0), hi0 = bfh(d0);
      acc[0]  = fmaf(wa0.x, lo0, acc[0]);  acc[1]  = fmaf(wa0.x, hi0, acc[1]);
      acc[2]  = fmaf(wa0.y, lo0, acc[2]);  acc[3]  = fmaf(wa0.y, hi0, acc[3]);
      acc[4]  = fmaf(wa0.z, lo0, acc[4]);  acc[5]  = fmaf(wa0.z, hi0, acc[5]);
      acc[6]  = fmaf(wa0.w, lo0, acc[6]);  acc[7]  = fmaf(wa0.w, hi0, acc[7]);
      acc[8]  = fmaf(wb0.x, lo0, acc[8]);  acc[9]  = fmaf(wb0.x, hi0, acc[9]);
      acc[10] = fmaf(wb0.y, lo0, acc[10]); acc[11] = fmaf(wb0.y, hi0, acc[11]);
      acc[12] = fmaf(wb0.z, lo0, acc[12]); acc[13] = fmaf(wb0.z, hi0, acc[13]);
      acc[14] = fmaf(wb0.w, lo0, acc[14]); acc[15] = fmaf(wb0.w, hi0, acc[15]);
      const float lo1 = bfl(d1), hi1 = bfh(d1);
      acc[0]  = fmaf(wa1.x, lo1, acc[0]);  acc[1]  = fmaf(wa1.x, hi1, acc[1]);
      acc[2]  = fmaf(wa1.y, lo1, acc[2]);  acc[3]  = fmaf(wa1.y, hi1, acc[3]);
      acc[4]  = fmaf(wa1.z, lo1, acc[4]);  acc[5]  = fmaf(wa1.z, hi1, acc[5]);
      acc[6]  = fmaf(wa1.w, lo1, acc[6]);  acc[7]  = fmaf(wa1.w, hi1, acc[7]);
      acc[8]  = fmaf(wb1.x, lo1, acc[8]);  acc[9]  = fmaf(wb1.x, hi1, acc[9]);
      acc[10] = fmaf(wb1.y, lo1, acc[10]); acc[11] = fmaf(wb1.y, hi1, acc[11]);
      acc[12] = fmaf(wb1.z, lo1, acc[12]); acc[13] = fmaf(wb1.z, hi1, acc[13]);
      acc[14] = fmaf(wb1.w, lo1, acc[14]); acc[15] = fmaf(wb1.w, hi1, acc[15]);
    }

    __syncthreads();
    #pragma unroll
    for (int a = 0; a < 8; ++a) {
      sAcc[wv * 1024 + a * 128 + 2 * lane]     = acc[2 * a];
      sAcc[wv * 1024 + a * 128 + 2 * lane + 1] = acc[2 * a + 1];
    }
    __syncthreads();
    const int c = tid * 4;
    float4 s = {0.f, 0.f, 0.f, 0.f};
    #pragma unroll
    for (int w = 0; w < 4; ++w) {
      const float4 v = *(const float4*)&sAcc[w * 1024 + c];
      s.x += v.x; s.y += v.y; s.z += v.z; s.w += v.w;
    }
    *(float4*)&partial[(size_t)blockIdx.x * 1024 + c] = s;
  }

  grid_barrier(bar, bar + 16);

  // ---- P4: out[c] = sum_b partial[b][c]; blocks 0..3, coalesced, plain stores ----
  if (blockIdx.x < 4) {
    const int c = blockIdx.x * 256 + tid;
    const int nb = gridDim.x;
    float s = 0.f;
    #pragma unroll 8
    for (int j = 0; j < nb; ++j) s += partial[(size_t)j * 1024 + c];
    out[c] = s;
  }
}

extern "C" void kernel_launch(void* const* d_in, const int* in_sizes, int n_in,
                              void* d_out, int out_size, void* d_ws, size_t ws_size,
                              hipStream_t stream) {
  const float* node  = (const float*)d_in[0];
  const int* elist   = (const int*)d_in[2];
  const void* maskp  = (const void*)d_in[3];
  const float* W1    = (const float*)d_in[4];
  const float* a1    = (const float*)d_in[5];
  float* out         = (float*)d_out;

  int N = in_sizes[0] / 128;
  int M = in_sizes[2] / 8;

  char* ws = (char*)d_ws;
  unsigned short* Wh = (unsigned short*)ws;              // N*256 B
  size_t off = (size_t)N * 256;
  float* sigma = (float*)(ws + off);  off += (size_t)N * 4;
  off = (off + 255) & ~(size_t)255;
  float* W8 = (float*)(ws + off);
  const size_t zeroBytes = (size_t)N * 32 + 256;         // W8 + barrier state + flag
  int* bar  = (int*)(ws + off + (size_t)N * 32);         // [cnt, ..., gen at +16]
  int* flag = bar + 32;
  off += zeroBytes;
  off = (off + 255) & ~(size_t)255;
  float* partial = (float*)(ws + off);                   // grid x 1024 floats

  int dev = 0;
  (void)hipGetDevice(&dev);
  int cu = 0;
  (void)hipDeviceGetAttribute(&cu, hipDeviceAttributeMultiprocessorCount, dev);
  if (cu <= 0) cu = 256;
  int grid = 4 * cu;                 // co-resident per __launch_bounds__(256,4)
  if (grid > 1024) grid = 1024;

  (void)hipMemsetAsync(W8, 0, zeroBytes, stream);        // W8 + bar + flag = 0
  fused_all<<<grid, 256, 0, stream>>>(node, W1, a1, elist, maskp, Wh, sigma, W8,
                                      bar, flag, partial, out, N, M);
}

// Round 9
// 119.616 us; speedup vs baseline: 6.6819x; 6.6819x over previous
//
#include <hip/hip_runtime.h>

typedef unsigned int uint32;
typedef __attribute__((ext_vector_type(8))) short short8v;  // 8 bf16 (4 VGPRs)
typedef __attribute__((ext_vector_type(4))) float f32x4;

__device__ __forceinline__ unsigned short f2bf(float f) {
  unsigned u = __float_as_uint(f);
  return (unsigned short)((u + 0x7FFFu + ((u >> 16) & 1u)) >> 16);
}
__device__ __forceinline__ float bfl(unsigned x) { return __uint_as_float(x << 16); }
__device__ __forceinline__ float bfh(unsigned x) { return __uint_as_float(x & 0xFFFF0000u); }

// k1: Wh = X @ W1 via mfma_f32_16x16x32_bf16 + sigma epilogue + mask-dtype detect
// (block 0). Runs before k2a in stream order, so flag is ready when k2a reads it.
__global__ __launch_bounds__(256) void k1_mfma(const float* __restrict__ X,
                                               const float* __restrict__ W,
                                               const float* __restrict__ a1,
                                               const uint32* __restrict__ md,
                                               unsigned short* __restrict__ Wh,
                                               float* __restrict__ sigma,
                                               int* __restrict__ flag, int N) {
  __shared__ short sB[2048 * 8];  // 32 KiB
  const int tid = threadIdx.x;
  if (blockIdx.x == 0 && tid < 64) {
    bool ok4 = true;
    for (int i = tid; i < 1024; i += 64) {
      uint32 v = md[i];
      if (!(v == 0u || v == 1u || v == 0x3F800000u)) ok4 = false;
    }
    bool all4 = __all(ok4);
    if (tid == 0)
      __hip_atomic_store(flag, all4 ? 4 : 1, __ATOMIC_RELEASE, __HIP_MEMORY_SCOPE_AGENT);
  }
  for (int i = tid; i < 2048; i += 256) {
    const int frag = i >> 6, ln = i & 63;
    const int kt = frag >> 3, ct = frag & 7, p = ln >> 4, q = ln & 15;
    short8v v;
    #pragma unroll
    for (int j = 0; j < 8; ++j)
      v[j] = (short)f2bf(W[(kt * 32 + p * 8 + j) * 128 + ct * 16 + q]);
    *(short8v*)&sB[i * 8] = v;
  }
  __syncthreads();

  const int lane = tid & 63;
  const int p = lane >> 4, q = lane & 15;
  float a1v[8];
  #pragma unroll
  for (int ct = 0; ct < 8; ++ct) a1v[ct] = a1[ct * 16 + q];

  const int wave = blockIdx.x * 4 + (tid >> 6);
  const int nwaves = gridDim.x * 4;
  const int nstrips = (N + 15) >> 4;

  for (int s = wave; s < nstrips; s += nwaves) {
    const int row = s * 16 + q;
    const int rclamp = row < N ? row : (N - 1);
    const float* xr = X + (size_t)rclamp * 128 + p * 8;
    float4 L[8];
    #pragma unroll
    for (int kt = 0; kt < 4; ++kt) {
      L[2 * kt]     = *(const float4*)(xr + kt * 32);
      L[2 * kt + 1] = *(const float4*)(xr + kt * 32 + 4);
    }
    short8v A[4];
    #pragma unroll
    for (int kt = 0; kt < 4; ++kt) {
      #pragma unroll
      for (int j = 0; j < 4; ++j) {
        A[kt][j]     = (short)f2bf((&L[2 * kt].x)[j]);
        A[kt][j + 4] = (short)f2bf((&L[2 * kt + 1].x)[j]);
      }
    }
    f32x4 acc[8];
    #pragma unroll
    for (int ct = 0; ct < 8; ++ct) acc[ct] = (f32x4){0.f, 0.f, 0.f, 0.f};
    #pragma unroll
    for (int kt = 0; kt < 4; ++kt) {
      #pragma unroll
      for (int ct = 0; ct < 8; ++ct) {
        short8v b = *(const short8v*)&sB[((kt * 8 + ct) * 64 + lane) * 8];
        acc[ct] = __builtin_amdgcn_mfma_f32_16x16x32_bf16(A[kt], b, acc[ct], 0, 0, 0);
      }
    }
    const int r0 = s * 16 + p * 4;
    #pragma unroll
    for (int ct = 0; ct < 8; ++ct) {
      #pragma unroll
      for (int r = 0; r < 4; ++r) {
        const int rr = r0 + r;
        if (rr < N) Wh[(size_t)rr * 128 + ct * 16 + q] = f2bf(acc[ct][r]);
      }
    }
    #pragma unroll
    for (int r = 0; r < 4; ++r) {
      float tsum = 0.f;
      #pragma unroll
      for (int ct = 0; ct < 8; ++ct) {
        const float v = acc[ct][r];
        tsum += fmaxf(v, 0.2f * v) * a1v[ct];
      }
      tsum += __shfl_xor(tsum, 1);
      tsum += __shfl_xor(tsum, 2);
      tsum += __shfl_xor(tsum, 4);
      tsum += __shfl_xor(tsum, 8);
      const int rr = r0 + r;
      if (q == r && rr < N) sigma[rr] = tsum;
    }
  }
}

// k2a: one LANE per edge. Coalesced 32B idx + mask loads, 8 scalar sigma gathers
// (L2-resident 400KB table), in-lane softmax, ~4.5 atomicAdds into W8[n][a].
template <int MSZ>
__device__ __forceinline__ void k2a_body(const int* __restrict__ elist,
                                         const void* __restrict__ maskp,
                                         const float* __restrict__ sigma,
                                         float* __restrict__ W8, int m) {
  const int4 ia = ((const int4*)elist)[m * 2];
  const int4 ib = ((const int4*)elist)[m * 2 + 1];
  const int idx[8] = {ia.x, ia.y, ia.z, ia.w, ib.x, ib.y, ib.z, ib.w};
  int vld[8];
  if (MSZ == 4) {
    const int4 ma = ((const int4*)maskp)[m * 2];
    const int4 mb = ((const int4*)maskp)[m * 2 + 1];
    vld[0] = ma.x; vld[1] = ma.y; vld[2] = ma.z; vld[3] = ma.w;
    vld[4] = mb.x; vld[5] = mb.y; vld[6] = mb.z; vld[7] = mb.w;
  } else {
    const uint2 u = ((const uint2*)maskp)[m];
    vld[0] = u.x & 0xFF; vld[1] = (u.x >> 8) & 0xFF;
    vld[2] = (u.x >> 16) & 0xFF; vld[3] = u.x >> 24;
    vld[4] = u.y & 0xFF; vld[5] = (u.y >> 8) & 0xFF;
    vld[6] = (u.y >> 16) & 0xFF; vld[7] = u.y >> 24;
  }
  float sg[8];
  #pragma unroll
  for (int a = 0; a < 8; ++a) sg[a] = sigma[idx[a]];
  float mx = -3.0e38f;
  #pragma unroll
  for (int a = 0; a < 8; ++a) mx = fmaxf(mx, vld[a] ? sg[a] : -3.0e38f);
  float ev[8];
  float dn = 0.f;
  #pragma unroll
  for (int a = 0; a < 8; ++a) {
    ev[a] = vld[a] ? __expf(sg[a] - mx) : 0.f;
    dn += ev[a];
  }
  const float inv = __fdividef(1.f, dn);
  #pragma unroll
  for (int a = 0; a < 8; ++a)
    if (vld[a]) atomicAdd(&W8[(size_t)idx[a] * 8 + a], ev[a] * inv);
}

__global__ __launch_bounds__(256) void k2a_edges(const int* __restrict__ elist,
                                                 const void* __restrict__ maskp,
                                                 const float* __restrict__ sigma,
                                                 const int* __restrict__ flag,
                                                 float* __restrict__ W8, int M) {
  const int m = blockIdx.x * 256 + threadIdx.x;
  if (m >= M) return;
  const int msz = __hip_atomic_load(flag, __ATOMIC_ACQUIRE, __HIP_MEMORY_SCOPE_AGENT);
  if (msz == 4) k2a_body<4>(elist, maskp, sigma, W8, m);
  else          k2a_body<1>(elist, maskp, sigma, W8, m);
}

// k2b: partial[b] = sum_n W8[n][a] * Wh[n][f] over this block's slice.
// 4-node unroll: 12 independent load batches per wave (MLP), plain stores.
__global__ __launch_bounds__(256) void k2b_nodes(const uint32* __restrict__ Wh32,
                                                 const float* __restrict__ W8,
                                                 float* __restrict__ partial, int N) {
  __shared__ float sAcc[4][1024];
  const int lane = threadIdx.x & 63, wv = threadIdx.x >> 6;
  const int wave = blockIdx.x * 4 + wv, nw = gridDim.x * 4;
  float acc[16];
  #pragma unroll
  for (int j = 0; j < 16; ++j) acc[j] = 0.f;

  for (int n0 = wave; n0 < N; n0 += 4 * nw) {
    uint32 d[4];
    float4 wa[4], wb[4];
    #pragma unroll
    for (int u = 0; u < 4; ++u) {
      const int n = n0 + u * nw;
      const bool in = n < N;
      const int nc = in ? n : 0;
      d[u]  = Wh32[(size_t)nc * 64 + lane];
      wa[u] = *(const float4*)&W8[(size_t)nc * 8];
      wb[u] = *(const float4*)&W8[(size_t)nc * 8 + 4];
      if (!in) {
        d[u] = 0;
        wa[u] = (float4){0.f, 0.f, 0.f, 0.f};
        wb[u] = (float4){0.f, 0.f, 0.f, 0.f};
      }
    }
    #pragma unroll
    for (int u = 0; u < 4; ++u) {
      const float lo = bfl(d[u]), hi = bfh(d[u]);
      acc[0]  = fmaf(wa[u].x, lo, acc[0]);  acc[1]  = fmaf(wa[u].x, hi, acc[1]);
      acc[2]  = fmaf(wa[u].y, lo, acc[2]);  acc[3]  = fmaf(wa[u].y, hi, acc[3]);
      acc[4]  = fmaf(wa[u].z, lo, acc[4]);  acc[5]  = fmaf(wa[u].z, hi, acc[5]);
      acc[6]  = fmaf(wa[u].w, lo, acc[6]);  acc[7]  = fmaf(wa[u].w, hi, acc[7]);
      acc[8]  = fmaf(wb[u].x, lo, acc[8]);  acc[9]  = fmaf(wb[u].x, hi, acc[9]);
      acc[10] = fmaf(wb[u].y, lo, acc[10]); acc[11] = fmaf(wb[u].y, hi, acc[11]);
      acc[12] = fmaf(wb[u].z, lo, acc[12]); acc[13] = fmaf(wb[u].z, hi, acc[13]);
      acc[14] = fmaf(wb[u].w, lo, acc[14]); acc[15] = fmaf(wb[u].w, hi, acc[15]);
    }
  }

  #pragma unroll
  for (int a = 0; a < 8; ++a) {
    sAcc[wv][a * 128 + 2 * lane]     = acc[2 * a];
    sAcc[wv][a * 128 + 2 * lane + 1] = acc[2 * a + 1];
  }
  __syncthreads();
  const int c = threadIdx.x * 4;
  float4 s = {0.f, 0.f, 0.f, 0.f};
  #pragma unroll
  for (int w = 0; w < 4; ++w) {
    const float4 v = *(const float4*)&sAcc[w][c];
    s.x += v.x; s.y += v.y; s.z += v.z; s.w += v.w;
  }
  *(float4*)&partial[(size_t)blockIdx.x * 1024 + c] = s;
}

// k3: out[c] = sum_j partial[j][c]; plain stores (out needs no pre-zero).
__global__ __launch_bounds__(64) void k3_reduce(const float* __restrict__ partial,
                                                float* __restrict__ out, int nb) {
  const int c = blockIdx.x * 64 + threadIdx.x;
  float s = 0.f;
  #pragma unroll 16
  for (int j = 0; j < nb; ++j) s += partial[(size_t)j * 1024 + c];
  out[c] = s;
}

extern "C" void kernel_launch(void* const* d_in, const int* in_sizes, int n_in,
                              void* d_out, int out_size, void* d_ws, size_t ws_size,
                              hipStream_t stream) {
  const float* node  = (const float*)d_in[0];
  const int* elist   = (const int*)d_in[2];
  const void* maskp  = (const void*)d_in[3];
  const float* W1    = (const float*)d_in[4];
  const float* a1    = (const float*)d_in[5];
  float* out         = (float*)d_out;

  const int N = in_sizes[0] / 128;
  const int M = in_sizes[2] / 8;
  const int K2B_BLOCKS = 512;

  char* ws = (char*)d_ws;
  unsigned short* Wh = (unsigned short*)ws;              // N*256 B
  size_t off = (size_t)N * 256;
  float* sigma = (float*)(ws + off);  off += (size_t)N * 4;
  off = (off + 255) & ~(size_t)255;
  float* W8 = (float*)(ws + off);                        // N*32 B
  const size_t zeroBytes = (size_t)N * 32 + 256;         // W8 + flag
  int* flag = (int*)(ws + off + (size_t)N * 32);
  off += zeroBytes;
  off = (off + 255) & ~(size_t)255;
  float* partial = (float*)(ws + off);                   // K2B_BLOCKS*1024 floats

  (void)hipMemsetAsync(W8, 0, zeroBytes, stream);        // W8 + flag = 0
  k1_mfma<<<784, 256, 0, stream>>>(node, W1, a1, (const uint32*)maskp, Wh, sigma, flag, N);
  k2a_edges<<<(M + 255) / 256, 256, 0, stream>>>(elist, maskp, sigma, flag, W8, M);
  k2b_nodes<<<K2B_BLOCKS, 256, 0, stream>>>((const uint32*)Wh, W8, partial, N);
  k3_reduce<<<16, 64, 0, stream>>>(partial, out, K2B_BLOCKS);
}

// Round 10
// 113.945 us; speedup vs baseline: 7.0145x; 1.0498x over previous
//
#include <hip/hip_runtime.h>

typedef unsigned int uint32;
typedef __attribute__((ext_vector_type(8))) short short8v;  // 8 bf16 (4 VGPRs)
typedef __attribute__((ext_vector_type(4))) float f32x4;

__device__ __forceinline__ unsigned short f2bf(float f) {
  unsigned u = __float_as_uint(f);
  return (unsigned short)((u + 0x7FFFu + ((u >> 16) & 1u)) >> 16);
}
__device__ __forceinline__ float bfl(unsigned x) { return __uint_as_float(x << 16); }
__device__ __forceinline__ float bfh(unsigned x) { return __uint_as_float(x & 0xFFFF0000u); }

// k1: Wh = X @ W1 via mfma_f32_16x16x32_bf16 + sigma epilogue.
// Prologue: grid-stride zero of W8 (runtime fill kernel costs 39us for 3.2MB —
// measured R9 — so we do it ourselves, ~2us marginal) + mask-dtype detect (block 0).
__global__ __launch_bounds__(256) void k1_mfma(const float* __restrict__ X,
                                               const float* __restrict__ W,
                                               const float* __restrict__ a1,
                                               const uint32* __restrict__ md,
                                               unsigned short* __restrict__ Wh,
                                               float* __restrict__ sigma,
                                               float4* __restrict__ W8v,
                                               int* __restrict__ flag, int N) {
  __shared__ short sB[2048 * 8];  // 32 KiB
  const int tid = threadIdx.x;
  // zero W8 (N*8 floats = N*2 float4): stream-ordered before k2a's atomics
  {
    const int n4 = N * 2;
    const int gtid = blockIdx.x * 256 + tid;
    const int nth = gridDim.x * 256;
    for (int i = gtid; i < n4; i += nth) W8v[i] = (float4){0.f, 0.f, 0.f, 0.f};
  }
  if (blockIdx.x == 0 && tid < 64) {
    bool ok4 = true;
    for (int i = tid; i < 1024; i += 64) {
      uint32 v = md[i];
      if (!(v == 0u || v == 1u || v == 0x3F800000u)) ok4 = false;
    }
    bool all4 = __all(ok4);
    if (tid == 0)
      __hip_atomic_store(flag, all4 ? 4 : 1, __ATOMIC_RELEASE, __HIP_MEMORY_SCOPE_AGENT);
  }
  for (int i = tid; i < 2048; i += 256) {
    const int frag = i >> 6, ln = i & 63;
    const int kt = frag >> 3, ct = frag & 7, p = ln >> 4, q = ln & 15;
    short8v v;
    #pragma unroll
    for (int j = 0; j < 8; ++j)
      v[j] = (short)f2bf(W[(kt * 32 + p * 8 + j) * 128 + ct * 16 + q]);
    *(short8v*)&sB[i * 8] = v;
  }
  __syncthreads();

  const int lane = tid & 63;
  const int p = lane >> 4, q = lane & 15;
  float a1v[8];
  #pragma unroll
  for (int ct = 0; ct < 8; ++ct) a1v[ct] = a1[ct * 16 + q];

  const int wave = blockIdx.x * 4 + (tid >> 6);
  const int nwaves = gridDim.x * 4;
  const int nstrips = (N + 15) >> 4;

  for (int s = wave; s < nstrips; s += nwaves) {
    const int row = s * 16 + q;
    const int rclamp = row < N ? row : (N - 1);
    const float* xr = X + (size_t)rclamp * 128 + p * 8;
    float4 L[8];
    #pragma unroll
    for (int kt = 0; kt < 4; ++kt) {
      L[2 * kt]     = *(const float4*)(xr + kt * 32);
      L[2 * kt + 1] = *(const float4*)(xr + kt * 32 + 4);
    }
    short8v A[4];
    #pragma unroll
    for (int kt = 0; kt < 4; ++kt) {
      #pragma unroll
      for (int j = 0; j < 4; ++j) {
        A[kt][j]     = (short)f2bf((&L[2 * kt].x)[j]);
        A[kt][j + 4] = (short)f2bf((&L[2 * kt + 1].x)[j]);
      }
    }
    f32x4 acc[8];
    #pragma unroll
    for (int ct = 0; ct < 8; ++ct) acc[ct] = (f32x4){0.f, 0.f, 0.f, 0.f};
    #pragma unroll
    for (int kt = 0; kt < 4; ++kt) {
      #pragma unroll
      for (int ct = 0; ct < 8; ++ct) {
        short8v b = *(const short8v*)&sB[((kt * 8 + ct) * 64 + lane) * 8];
        acc[ct] = __builtin_amdgcn_mfma_f32_16x16x32_bf16(A[kt], b, acc[ct], 0, 0, 0);
      }
    }
    const int r0 = s * 16 + p * 4;
    #pragma unroll
    for (int ct = 0; ct < 8; ++ct) {
      #pragma unroll
      for (int r = 0; r < 4; ++r) {
        const int rr = r0 + r;
        if (rr < N) Wh[(size_t)rr * 128 + ct * 16 + q] = f2bf(acc[ct][r]);
      }
    }
    #pragma unroll
    for (int r = 0; r < 4; ++r) {
      float tsum = 0.f;
      #pragma unroll
      for (int ct = 0; ct < 8; ++ct) {
        const float v = acc[ct][r];
        tsum += fmaxf(v, 0.2f * v) * a1v[ct];
      }
      tsum += __shfl_xor(tsum, 1);
      tsum += __shfl_xor(tsum, 2);
      tsum += __shfl_xor(tsum, 4);
      tsum += __shfl_xor(tsum, 8);
      const int rr = r0 + r;
      if (q == r && rr < N) sigma[rr] = tsum;
    }
  }
}

// k2a: one LANE per edge. Coalesced 32B idx + mask loads, 8 scalar sigma gathers
// (L2-resident 400KB table), in-lane softmax, ~4.5 atomicAdds into W8[n][a].
template <int MSZ>
__device__ __forceinline__ void k2a_body(const int* __restrict__ elist,
                                         const void* __restrict__ maskp,
                                         const float* __restrict__ sigma,
                                         float* __restrict__ W8, int m) {
  const int4 ia = ((const int4*)elist)[m * 2];
  const int4 ib = ((const int4*)elist)[m * 2 + 1];
  const int idx[8] = {ia.x, ia.y, ia.z, ia.w, ib.x, ib.y, ib.z, ib.w};
  int vld[8];
  if (MSZ == 4) {
    const int4 ma = ((const int4*)maskp)[m * 2];
    const int4 mb = ((const int4*)maskp)[m * 2 + 1];
    vld[0] = ma.x; vld[1] = ma.y; vld[2] = ma.z; vld[3] = ma.w;
    vld[4] = mb.x; vld[5] = mb.y; vld[6] = mb.z; vld[7] = mb.w;
  } else {
    const uint2 u = ((const uint2*)maskp)[m];
    vld[0] = u.x & 0xFF; vld[1] = (u.x >> 8) & 0xFF;
    vld[2] = (u.x >> 16) & 0xFF; vld[3] = u.x >> 24;
    vld[4] = u.y & 0xFF; vld[5] = (u.y >> 8) & 0xFF;
    vld[6] = (u.y >> 16) & 0xFF; vld[7] = u.y >> 24;
  }
  float sg[8];
  #pragma unroll
  for (int a = 0; a < 8; ++a) sg[a] = sigma[idx[a]];
  float mx = -3.0e38f;
  #pragma unroll
  for (int a = 0; a < 8; ++a) mx = fmaxf(mx, vld[a] ? sg[a] : -3.0e38f);
  float ev[8];
  float dn = 0.f;
  #pragma unroll
  for (int a = 0; a < 8; ++a) {
    ev[a] = vld[a] ? __expf(sg[a] - mx) : 0.f;
    dn += ev[a];
  }
  const float inv = __fdividef(1.f, dn);
  #pragma unroll
  for (int a = 0; a < 8; ++a)
    if (vld[a]) atomicAdd(&W8[(size_t)idx[a] * 8 + a], ev[a] * inv);
}

__global__ __launch_bounds__(256) void k2a_edges(const int* __restrict__ elist,
                                                 const void* __restrict__ maskp,
                                                 const float* __restrict__ sigma,
                                                 const int* __restrict__ flag,
                                                 float* __restrict__ W8, int M) {
  const int m = blockIdx.x * 256 + threadIdx.x;
  if (m >= M) return;
  const int msz = __hip_atomic_load(flag, __ATOMIC_ACQUIRE, __HIP_MEMORY_SCOPE_AGENT);
  if (msz == 4) k2a_body<4>(elist, maskp, sigma, W8, m);
  else          k2a_body<1>(elist, maskp, sigma, W8, m);
}

// k2b: partial[b] = sum_n W8[n][a] * Wh[n][f] over this block's slice.
// 4-node unroll: 12 independent load batches per wave (MLP), plain stores.
__global__ __launch_bounds__(256) void k2b_nodes(const uint32* __restrict__ Wh32,
                                                 const float* __restrict__ W8,
                                                 float* __restrict__ partial, int N) {
  __shared__ float sAcc[4][1024];
  const int lane = threadIdx.x & 63, wv = threadIdx.x >> 6;
  const int wave = blockIdx.x * 4 + wv, nw = gridDim.x * 4;
  float acc[16];
  #pragma unroll
  for (int j = 0; j < 16; ++j) acc[j] = 0.f;

  for (int n0 = wave; n0 < N; n0 += 4 * nw) {
    uint32 d[4];
    float4 wa[4], wb[4];
    #pragma unroll
    for (int u = 0; u < 4; ++u) {
      const int n = n0 + u * nw;
      const bool in = n < N;
      const int nc = in ? n : 0;
      d[u]  = Wh32[(size_t)nc * 64 + lane];
      wa[u] = *(const float4*)&W8[(size_t)nc * 8];
      wb[u] = *(const float4*)&W8[(size_t)nc * 8 + 4];
      if (!in) {
        d[u] = 0;
        wa[u] = (float4){0.f, 0.f, 0.f, 0.f};
        wb[u] = (float4){0.f, 0.f, 0.f, 0.f};
      }
    }
    #pragma unroll
    for (int u = 0; u < 4; ++u) {
      const float lo = bfl(d[u]), hi = bfh(d[u]);
      acc[0]  = fmaf(wa[u].x, lo, acc[0]);  acc[1]  = fmaf(wa[u].x, hi, acc[1]);
      acc[2]  = fmaf(wa[u].y, lo, acc[2]);  acc[3]  = fmaf(wa[u].y, hi, acc[3]);
      acc[4]  = fmaf(wa[u].z, lo, acc[4]);  acc[5]  = fmaf(wa[u].z, hi, acc[5]);
      acc[6]  = fmaf(wa[u].w, lo, acc[6]);  acc[7]  = fmaf(wa[u].w, hi, acc[7]);
      acc[8]  = fmaf(wb[u].x, lo, acc[8]);  acc[9]  = fmaf(wb[u].x, hi, acc[9]);
      acc[10] = fmaf(wb[u].y, lo, acc[10]); acc[11] = fmaf(wb[u].y, hi, acc[11]);
      acc[12] = fmaf(wb[u].z, lo, acc[12]); acc[13] = fmaf(wb[u].z, hi, acc[13]);
      acc[14] = fmaf(wb[u].w, lo, acc[14]); acc[15] = fmaf(wb[u].w, hi, acc[15]);
    }
  }

  #pragma unroll
  for (int a = 0; a < 8; ++a) {
    sAcc[wv][a * 128 + 2 * lane]     = acc[2 * a];
    sAcc[wv][a * 128 + 2 * lane + 1] = acc[2 * a + 1];
  }
  __syncthreads();
  const int c = threadIdx.x * 4;
  float4 s = {0.f, 0.f, 0.f, 0.f};
  #pragma unroll
  for (int w = 0; w < 4; ++w) {
    const float4 v = *(const float4*)&sAcc[w][c];
    s.x += v.x; s.y += v.y; s.z += v.z; s.w += v.w;
  }
  *(float4*)&partial[(size_t)blockIdx.x * 1024 + c] = s;
}

// k3: out[c] = sum_j partial[j][c]; plain stores (out needs no pre-zero).
__global__ __launch_bounds__(64) void k3_reduce(const float* __restrict__ partial,
                                                float* __restrict__ out, int nb) {
  const int c = blockIdx.x * 64 + threadIdx.x;
  float s = 0.f;
  #pragma unroll 16
  for (int j = 0; j < nb; ++j) s += partial[(size_t)j * 1024 + c];
  out[c] = s;
}

extern "C" void kernel_launch(void* const* d_in, const int* in_sizes, int n_in,
                              void* d_out, int out_size, void* d_ws, size_t ws_size,
                              hipStream_t stream) {
  const float* node  = (const float*)d_in[0];
  const int* elist   = (const int*)d_in[2];
  const void* maskp  = (const void*)d_in[3];
  const float* W1    = (const float*)d_in[4];
  const float* a1    = (const float*)d_in[5];
  float* out         = (float*)d_out;

  const int N = in_sizes[0] / 128;
  const int M = in_sizes[2] / 8;
  const int K2B_BLOCKS = 512;

  char* ws = (char*)d_ws;
  unsigned short* Wh = (unsigned short*)ws;              // N*256 B
  size_t off = (size_t)N * 256;
  float* sigma = (float*)(ws + off);  off += (size_t)N * 4;
  off = (off + 255) & ~(size_t)255;
  float* W8 = (float*)(ws + off);                        // N*32 B
  int* flag = (int*)(ws + off + (size_t)N * 32);
  off += (size_t)N * 32 + 256;
  off = (off + 255) & ~(size_t)255;
  float* partial = (float*)(ws + off);                   // K2B_BLOCKS*1024 floats

  k1_mfma<<<784, 256, 0, stream>>>(node, W1, a1, (const uint32*)maskp, Wh, sigma,
                                   (float4*)W8, flag, N);
  k2a_edges<<<(M + 255) / 256, 256, 0, stream>>>(elist, maskp, sigma, flag, W8, M);
  k2b_nodes<<<K2B_BLOCKS, 256, 0, stream>>>((const uint32*)Wh, W8, partial, N);
  k3_reduce<<<16, 64, 0, stream>>>(partial, out, K2B_BLOCKS);
}